// Round 1
// baseline (321.820 us; speedup 1.0000x reference)
//
#include <hip/hip_runtime.h>
#include <hip/hip_bf16.h>

// CRF negative log-likelihood, B=256, T=1024, L=64 label states.
// Forward recursion done in log2 domain with V = exp(T) precomputed in VGPRs:
//   alpha2'[j] = pred[t,j]*L2E + M2 + log2( sum_i exp2(alpha2[i]-M2) * V[i][j] )
// One wave per batch (lane j = state j). States 64/65 (begin/stop) drop out
// exactly in fp32 (exp(-1000) == 0) except at init / epilogue.

#define RL_F(x, i) __uint_as_float(__builtin_amdgcn_readlane(__float_as_uint(x), (i)))

__global__ __launch_bounds__(128) void crf_kernel(
    const float* __restrict__ pred,     // [256,1024,64]
    const float* __restrict__ trans,    // [66,66]
    const int*   __restrict__ ref,      // [256,1024]
    const int*   __restrict__ seqlen,   // [256]
    float* __restrict__ out)            // [1], pre-zeroed
{
    constexpr float L2E = 1.44269504088896340736f;  // log2(e)
    constexpr float LN2 = 0.69314718055994530942f;  // ln(2)
    const int b    = blockIdx.x;
    const int lane = threadIdx.x & 63;
    const int sl   = seqlen[b];

    if (threadIdx.x >= 64) {
        // ---- gold-path wave: emission + transition scores ----
        const int*   rb = ref  + b * 1024;
        const float* pg = pred + (size_t)b * 65536;
        float acc = 0.f;
        for (int t = lane; t <= sl; t += 64) {
            int from = (t == 0)  ? 64 : rb[t - 1];
            int cur  = (t < sl)  ? rb[t] : 65;   // at t==sl the "to" node is stop (65)
            acc += trans[from * 66 + cur];
            if (t < sl) acc += pg[t * 64 + cur]; // emission pred[b,t,ref[b,t]]
        }
        #pragma unroll
        for (int off = 32; off; off >>= 1) acc += __shfl_xor(acc, off, 64);
        if (lane == 0) atomicAdd(out, -acc);
        return;
    }

    // ---- forward wave: lane j owns state j ----
    // V[i] = exp(T[i][j]) for this lane's column j (64 VGPRs).
    float V[64];
    #pragma unroll
    for (int i = 0; i < 64; ++i)
        V[i] = __builtin_amdgcn_exp2f(trans[i * 66 + lane] * L2E);

    const float* pb = pred + (size_t)b * 65536 + lane;

    // t = 1: alpha_1[j] = pred[b,0,j] + T[64][j]   (log2 domain)
    float alpha2 = (pb[0] + trans[64 * 66 + lane]) * L2E;
    float M2 = RL_F(alpha2, 0);   // wave-uniform normalizer, lagged one step

    // One recursion step consuming pred row (t-1), value p = pred[b,t-1,lane].
    auto STEP = [&](float p) {
        float u = __builtin_amdgcn_exp2f(alpha2 - M2);
        float s0 = 0.f, s1 = 0.f, s2 = 0.f, s3 = 0.f;
        #pragma unroll
        for (int i = 0; i < 64; i += 4) {
            s0 = fmaf(RL_F(u, i + 0), V[i + 0], s0);
            s1 = fmaf(RL_F(u, i + 1), V[i + 1], s1);
            s2 = fmaf(RL_F(u, i + 2), V[i + 2], s2);
            s3 = fmaf(RL_F(u, i + 3), V[i + 3], s3);
        }
        float s = (s0 + s1) + (s2 + s3);
        alpha2 = fmaf(p, L2E, M2 + __builtin_amdgcn_logf(s));  // logf builtin = log2
        M2 = RL_F(alpha2, 0);
    };

    // Rolling 4-deep prefetch of pred rows; row r = pred[b, r, lane].
    auto ROW = [&](int r) { int rc = r < 1023 ? r : 1023; return pb[rc * 64]; };

    float p0 = ROW(1), p1 = ROW(2), p2 = ROW(3), p3 = ROW(4);
    int t = 2;
    for (; t + 3 <= sl; t += 4) {
        // prefetch rows (t+3 .. t+6) for steps t+4..t+7
        float n0 = ROW(t + 3), n1 = ROW(t + 4), n2 = ROW(t + 5), n3 = ROW(t + 6);
        STEP(p0); STEP(p1); STEP(p2); STEP(p3);
        p0 = n0; p1 = n1; p2 = n2; p3 = n3;
    }
    if (t <= sl) { STEP(p0); ++t; }
    if (t <= sl) { STEP(p1); ++t; }
    if (t <= sl) { STEP(p2); ++t; }

    // Epilogue: score_b = ln2 * lse2_i( alpha2[i] + T[i][65]*L2E )
    float aE = fmaf(trans[lane * 66 + 65], L2E, alpha2);
    float m = aE;
    #pragma unroll
    for (int off = 32; off; off >>= 1) m = fmaxf(m, __shfl_xor(m, off, 64));
    float e = __builtin_amdgcn_exp2f(aE - m);
    #pragma unroll
    for (int off = 32; off; off >>= 1) e += __shfl_xor(e, off, 64);
    if (lane == 0) atomicAdd(out, LN2 * (m + __builtin_amdgcn_logf(e)));
}

extern "C" void kernel_launch(void* const* d_in, const int* in_sizes, int n_in,
                              void* d_out, int out_size, void* d_ws, size_t ws_size,
                              hipStream_t stream) {
    const float* pred   = (const float*)d_in[0];
    const float* trans  = (const float*)d_in[1];
    const int*   ref    = (const int*)d_in[2];
    const int*   seqlen = (const int*)d_in[3];
    float* out = (float*)d_out;
    hipMemsetAsync(out, 0, sizeof(float), stream);
    crf_kernel<<<256, 128, 0, stream>>>(pred, trans, ref, seqlen, out);
}

// Round 2
// 213.436 us; speedup vs baseline: 1.5078x; 1.5078x over previous
//
#include <hip/hip_runtime.h>
#include <hip/hip_bf16.h>

// CRF NLL, B=256, T=1024, L=64. Linear-domain forward algebra:
//   alpha_{t+1} = E_{t+1} (.) (V^T alpha_t),  V = exp(trans), E_t = exp(pred[t-1])
// renormalized every step by 2^-k (k = IEEE exponent of lane 0, accumulated as int).
// Meet-in-the-middle: Z = alpha_h . beta_h with beta_{t-1} = V (E_t (.) beta_t),
// forward wave does t=2..h, backward wave does t=sl..h+1  (h ~ sl/2) -> serial
// chain halved. Wave 2 computes the gold-path score. States 64/65 drop out
// exactly in fp32 except at init (T[64][:]) and seed (T[:][65]).

#define RL_F(x, i) __uint_as_float(__builtin_amdgcn_readlane(__float_as_uint(x), (i)))

__device__ __constant__ float kL2E = 1.44269504088896340736f;
#define L2E  1.44269504088896340736f
#define LN2  0.69314718055994530942f

template<bool PREMUL>
__device__ __forceinline__ void run_chain(const float* __restrict__ pb,
                                          const float (&V)[64],
                                          float& a, int& K,
                                          int rstart, int dir, int nsteps)
{
    auto ROWF = [&](int idx) {
        idx = idx < 0 ? 0 : (idx > 1023 ? 1023 : idx);
        return pb[idx * 64];
    };
    auto STEP = [&](float p) {
        float E = __builtin_amdgcn_exp2f(p * L2E);          // e^pred
        float x = PREMUL ? a * E : a;                       // bwd: weight first
        float s0 = 0.f, s1 = 0.f, s2 = 0.f, s3 = 0.f;
        #pragma unroll
        for (int i = 0; i < 64; i += 4) {
            s0 = fmaf(RL_F(x, i + 0), V[i + 0], s0);
            s1 = fmaf(RL_F(x, i + 1), V[i + 1], s1);
            s2 = fmaf(RL_F(x, i + 2), V[i + 2], s2);
            s3 = fmaf(RL_F(x, i + 3), V[i + 3], s3);
        }
        float s = (s0 + s1) + (s2 + s3);
        a = PREMUL ? s : s * E;                             // fwd: emission after
        // exact renorm: k = exponent of lane0's a (bounded, never denormal)
        unsigned abits = (unsigned)__builtin_amdgcn_readfirstlane((int)__float_as_uint(a));
        int k = (int)((abits >> 23) & 255u) - 127;
        K += k;
        a *= __uint_as_float((unsigned)(127 - k) << 23);    // 2^-k
    };
    int r = rstart, n = nsteps;
    float p0 = ROWF(r), p1 = ROWF(r + dir), p2 = ROWF(r + 2 * dir), p3 = ROWF(r + 3 * dir);
    while (n >= 4) {
        float q0 = ROWF(r + 4 * dir), q1 = ROWF(r + 5 * dir),
              q2 = ROWF(r + 6 * dir), q3 = ROWF(r + 7 * dir);
        STEP(p0); STEP(p1); STEP(p2); STEP(p3);
        p0 = q0; p1 = q1; p2 = q2; p3 = q3;
        r += 4 * dir; n -= 4;
    }
    if (n > 0) { STEP(p0); --n; }
    if (n > 0) { STEP(p1); --n; }
    if (n > 0) { STEP(p2); --n; }
}

__global__ __launch_bounds__(192, 1) void crf_kernel(
    const float* __restrict__ pred,     // [256,1024,64]
    const float* __restrict__ trans,    // [66,66]
    const int*   __restrict__ ref,      // [256,1024]
    const int*   __restrict__ seqlen,   // [256]
    float* __restrict__ out)            // [1], pre-zeroed
{
    const int b    = blockIdx.x;
    const int lane = threadIdx.x & 63;
    const int wv   = threadIdx.x >> 6;
    const int sl   = seqlen[b];
    const int h    = (sl + 1) >> 1;

    __shared__ float sh_a[64];
    __shared__ int   sh_kf;

    if (wv == 2) {
        // ---- gold-path wave ----
        const int*   rb = ref  + b * 1024;
        const float* pg = pred + (size_t)b * 65536;
        float acc = 0.f;
        for (int t = lane; t <= sl; t += 64) {
            int from = (t == 0) ? 64 : rb[t - 1];
            int cur  = (t < sl) ? rb[t] : 65;
            acc += trans[from * 66 + cur];
            if (t < sl) acc += pg[t * 64 + cur];
        }
        #pragma unroll
        for (int off = 32; off; off >>= 1) acc += __shfl_xor(acc, off, 64);
        if (lane == 0) atomicAdd(out, -acc);
    } else {
        // ---- forward (wv==0) / backward (wv==1) chain waves ----
        float V[64];
        if (wv == 0) {
            #pragma unroll
            for (int q = 0; q < 64; ++q)            // column j = lane
                V[q] = __builtin_amdgcn_exp2f(trans[q * 66 + lane] * L2E);
        } else {
            #pragma unroll
            for (int q = 0; q < 64; ++q)            // row i = lane
                V[q] = __builtin_amdgcn_exp2f(trans[lane * 66 + q] * L2E);
        }

        const float* pb = pred + (size_t)b * 65536 + lane;
        float a;
        int   K = 0;
        if (wv == 0) {
            // alpha_1 = exp(pred[0] + T[64][:])
            a = __builtin_amdgcn_exp2f((pb[0] + trans[64 * 66 + lane]) * L2E);
            run_chain<false>(pb, V, a, K, /*rstart=*/1, /*dir=*/+1, /*nsteps=*/h - 1);
            sh_a[lane] = a;
            if (lane == 0) sh_kf = K;
        } else {
            // beta_sl = exp(T[:][65])
            a = __builtin_amdgcn_exp2f(trans[lane * 66 + 65] * L2E);
            run_chain<true>(pb, V, a, K, /*rstart=*/sl - 1, /*dir=*/-1, /*nsteps=*/sl - h);
        }
    }

    __syncthreads();

    if (wv == 1) {
        // Z = alpha_h . beta_h ; score = ln2 * (log2 Z + Kf + Kb)
        float z = sh_a[lane] * __uint_as_float(__float_as_uint(
                      // re-materialize this wave's beta from its own register: we
                      // still hold `a` only inside the else-branch scope, so redo:
                      0u));
        (void)z;
    }
    // NOTE: combine must see backward wave's a/K — recompute structure below.
}

// The combine above needs backward-wave state after the barrier; restructure via a
// second kernel-level path: do everything in one kernel with persistent locals.
__global__ __launch_bounds__(192, 1) void crf_kernel2(
    const float* __restrict__ pred,
    const float* __restrict__ trans,
    const int*   __restrict__ ref,
    const int*   __restrict__ seqlen,
    float* __restrict__ out)
{
    const int b    = blockIdx.x;
    const int lane = threadIdx.x & 63;
    const int wv   = threadIdx.x >> 6;
    const int sl   = seqlen[b];
    const int h    = (sl + 1) >> 1;

    __shared__ float sh_a[64];
    __shared__ int   sh_kf;

    float a = 0.f;
    int   K = 0;

    if (wv == 2) {
        const int*   rb = ref  + b * 1024;
        const float* pg = pred + (size_t)b * 65536;
        float acc = 0.f;
        for (int t = lane; t <= sl; t += 64) {
            int from = (t == 0) ? 64 : rb[t - 1];
            int cur  = (t < sl) ? rb[t] : 65;
            acc += trans[from * 66 + cur];
            if (t < sl) acc += pg[t * 64 + cur];
        }
        #pragma unroll
        for (int off = 32; off; off >>= 1) acc += __shfl_xor(acc, off, 64);
        if (lane == 0) atomicAdd(out, -acc);
    } else {
        float V[64];
        if (wv == 0) {
            #pragma unroll
            for (int q = 0; q < 64; ++q)
                V[q] = __builtin_amdgcn_exp2f(trans[q * 66 + lane] * L2E);
        } else {
            #pragma unroll
            for (int q = 0; q < 64; ++q)
                V[q] = __builtin_amdgcn_exp2f(trans[lane * 66 + q] * L2E);
        }
        const float* pb = pred + (size_t)b * 65536 + lane;
        if (wv == 0) {
            a = __builtin_amdgcn_exp2f((pb[0] + trans[64 * 66 + lane]) * L2E);
            run_chain<false>(pb, V, a, K, 1, +1, h - 1);
            sh_a[lane] = a;
            if (lane == 0) sh_kf = K;
        } else {
            a = __builtin_amdgcn_exp2f(trans[lane * 66 + 65] * L2E);
            run_chain<true>(pb, V, a, K, sl - 1, -1, sl - h);
        }
    }

    __syncthreads();

    if (wv == 1) {
        float z = sh_a[lane] * a;
        #pragma unroll
        for (int off = 32; off; off >>= 1) z += __shfl_xor(z, off, 64);
        if (lane == 0) {
            float res = LN2 * (__builtin_amdgcn_logf(z) + (float)(K + sh_kf));
            atomicAdd(out, res);
        }
    }
}

extern "C" void kernel_launch(void* const* d_in, const int* in_sizes, int n_in,
                              void* d_out, int out_size, void* d_ws, size_t ws_size,
                              hipStream_t stream) {
    const float* pred   = (const float*)d_in[0];
    const float* trans  = (const float*)d_in[1];
    const int*   ref    = (const int*)d_in[2];
    const int*   seqlen = (const int*)d_in[3];
    float* out = (float*)d_out;
    hipMemsetAsync(out, 0, sizeof(float), stream);
    crf_kernel2<<<256, 192, 0, stream>>>(pred, trans, ref, seqlen, out);
}